// Round 6
// baseline (216.287 us; speedup 1.0000x reference)
//
#include <hip/hip_runtime.h>

#define D_MODEL 512
#define NH 8
#define DK 64
#define SEQ 2048
#define NB 4

typedef __bf16 bf16x8 __attribute__((ext_vector_type(8)));
typedef float floatx4 __attribute__((ext_vector_type(4)));
typedef float floatx16 __attribute__((ext_vector_type(16)));

typedef __attribute__((address_space(1))) const unsigned int glb_u32;
typedef __attribute__((address_space(3))) unsigned int lds_u32;

__device__ __forceinline__ void gload_lds16(const unsigned short* g, unsigned short* l) {
    __builtin_amdgcn_global_load_lds((glb_u32*)g, (lds_u32*)l, 16, 0, 0);
}

// round-half-up bf16, packed pair via v_perm
__device__ inline unsigned int pack2bf(float lo, float hi) {
    unsigned int a = __float_as_uint(lo) + 0x8000u;
    unsigned int b = __float_as_uint(hi) + 0x8000u;
    return __builtin_amdgcn_perm(b, a, 0x07060302u);
}
__device__ inline unsigned short f2bf(float f) {
    return (unsigned short)((__float_as_uint(f) + 0x8000u) >> 16);
}
// scale a packed bf16 pair by s, repack
__device__ inline unsigned int scale2bf(unsigned int u, float s) {
    float lo = __uint_as_float(u << 16) * s;
    float hi = __uint_as_float(u & 0xFFFF0000u) * s;
    return pack2bf(lo, hi);
}

// ---------------------------------------------------------------------------
// Kernel 1: fused convert+QKV projection. fp32 in, register staging (R2-style,
// stride-40 LDS), R4 epilogue (LDS transpose + coalesced stores).
// C[8192][512] = X @ W^T + b. Q,K -> [b,h,s,dk]; V -> [b,h,dk,s].
// grid (4, 64, 3), block 256, tile 128x128, BK=32.
// ---------------------------------------------------------------------------
__global__ __launch_bounds__(256) void proj_qkv_kernel(
    const float* __restrict__ q, const float* __restrict__ k, const float* __restrict__ v,
    const float* __restrict__ wq, const float* __restrict__ wk, const float* __restrict__ wv,
    const float* __restrict__ bq, const float* __restrict__ bk, const float* __restrict__ bv,
    unsigned short* __restrict__ Qh, unsigned short* __restrict__ Kh,
    unsigned short* __restrict__ VhT)
{
    const int which = blockIdx.z;
    const float* X    = (which == 0) ? q  : (which == 1) ? k  : v;
    const float* W    = (which == 0) ? wq : (which == 1) ? wk : wv;
    const float* bias = (which == 0) ? bq : (which == 1) ? bk : bv;

    const int n0 = blockIdx.x * 128;
    const int m0 = blockIdx.y * 128;

    // staging: Al [128][40] @0, Bl [128][40] @5120 ; epilogue C [128][136]
    __shared__ unsigned short lds[17408];

    const int tid  = threadIdx.x;
    const int lane = tid & 63;
    const int wid  = tid >> 6;
    const int quad = lane >> 4;
    const int l16  = lane & 15;
    const int wr   = (wid >> 1) * 64;
    const int wc   = (wid & 1) * 64;

    floatx4 acc[4][4];
#pragma unroll
    for (int i = 0; i < 4; ++i)
#pragma unroll
        for (int j = 0; j < 4; ++j) acc[i][j] = {0.f, 0.f, 0.f, 0.f};

    for (int kt = 0; kt < 16; ++kt) {
        const int kk0 = kt * 32;
        __syncthreads();
        // stage A and B tiles (128 x 32, fp32 -> bf16): 4 float4/thread each
#pragma unroll
        for (int i = 0; i < 4; ++i) {
            int f   = tid + i * 256;
            int row = f >> 3;
            int kq  = (f & 7) * 4;
            float4 a4 = *(const float4*)(X + (size_t)(m0 + row) * 512 + kk0 + kq);
            uint2 ap2; ap2.x = pack2bf(a4.x, a4.y); ap2.y = pack2bf(a4.z, a4.w);
            *(uint2*)(&lds[row * 40 + kq]) = ap2;
            float4 b4 = *(const float4*)(W + (size_t)(n0 + row) * 512 + kk0 + kq);
            uint2 bp2; bp2.x = pack2bf(b4.x, b4.y); bp2.y = pack2bf(b4.z, b4.w);
            *(uint2*)(&lds[5120 + row * 40 + kq]) = bp2;
        }
        __syncthreads();

        bf16x8 af[4], bfr[4];
#pragma unroll
        for (int mi = 0; mi < 4; ++mi)
            af[mi] = *(const bf16x8*)(&lds[(wr + mi * 16 + l16) * 40 + quad * 8]);
#pragma unroll
        for (int ni = 0; ni < 4; ++ni)
            bfr[ni] = *(const bf16x8*)(&lds[5120 + (wc + ni * 16 + l16) * 40 + quad * 8]);
#pragma unroll
        for (int mi = 0; mi < 4; ++mi)
#pragma unroll
            for (int ni = 0; ni < 4; ++ni)
                acc[mi][ni] = __builtin_amdgcn_mfma_f32_16x16x32_bf16(
                    af[mi], bfr[ni], acc[mi][ni], 0, 0, 0);
    }

    // epilogue: acc (+bias) -> LDS C-tile [128][136] bf16 -> coalesced stores
    float bs[4];
#pragma unroll
    for (int ni = 0; ni < 4; ++ni) bs[ni] = bias[n0 + wc + ni * 16 + l16];

    __syncthreads();
#pragma unroll
    for (int mi = 0; mi < 4; ++mi)
#pragma unroll
        for (int ni = 0; ni < 4; ++ni)
#pragma unroll
            for (int r = 0; r < 4; ++r)
                lds[(wr + mi * 16 + quad * 4 + r) * 136 + wc + ni * 16 + l16] =
                    f2bf(acc[mi][ni][r] + bs[ni]);
    __syncthreads();

    const int b = m0 >> 11;
    if (which != 2) {
        unsigned short* dst = (which == 0) ? Qh : Kh;
#pragma unroll
        for (int j = 0; j < 8; ++j) {
            const int chunk = j * 256 + tid;
            const int srow  = chunk >> 4;
            const int col   = (chunk & 15) * 8;
            const int h  = (n0 + col) >> 6;
            const int dk = col & 63;
            const int s  = (m0 & 2047) + srow;
            uint4 vv = *(const uint4*)(&lds[srow * 136 + col]);
            *(uint4*)(dst + ((size_t)(b * NH + h) * SEQ + s) * DK + dk) = vv;
        }
    } else {
#pragma unroll
        for (int j = 0; j < 8; ++j) {
            const int chunk = j * 256 + tid;
            const int d    = chunk >> 4;
            const int sc8  = (chunk & 15) * 8;
            const int h  = (n0 + d) >> 6;
            const int dk = (n0 + d) & 63;
            unsigned short tmp[8];
#pragma unroll
            for (int i = 0; i < 8; ++i) tmp[i] = lds[(sc8 + i) * 136 + d];
            const size_t s0 = (size_t)(m0 & 2047) + sc8;
            *(uint4*)(VhT + ((size_t)(b * NH + h) * DK + dk) * SEQ + s0) = *(const uint4*)tmp;
        }
    }
}

// ---------------------------------------------------------------------------
// Kernel 2: flash attention v5 — R4 config (q-tile 128, 2 kg x 2 qw(64 rows),
// grid (16,8,4)) + DOUBLE-BUFFERED glds staging + row>>3 XOR swizzle.
// ---------------------------------------------------------------------------
__global__ __launch_bounds__(256, 2) void flash_kernel(
    const unsigned short* __restrict__ Qh, const unsigned short* __restrict__ Kh,
    const unsigned short* __restrict__ VhT, unsigned short* __restrict__ AO)
{
    const int qt = blockIdx.x, h = blockIdx.y, b = blockIdx.z;
    const size_t bh = (size_t)b * NH + h;
    const unsigned short* Qp = Qh + bh * SEQ * DK;
    const unsigned short* Kp = Kh + bh * SEQ * DK;
    const unsigned short* Vp = VhT + bh * DK * SEQ;

    // double-buffered staging: buf d @ d*16384, each [g][K 64x64 | V 64x64]
    __shared__ unsigned short smem[32768];   // 65,536 B

    const int tid  = threadIdx.x;
    const int lane = tid & 63;
    const int wid  = tid >> 6;
    const int g    = wid >> 1;    // k-group
    const int ws   = wid & 1;     // q-half (64 rows)
    const int hh   = lane >> 5;
    const int l32  = lane & 31;
    const int srow = lane >> 3;

    // ---- persistent Q fragments, pre-scaled by 0.125*log2(e) ----
    const float SC = 0.18033688f;
    bf16x8 qf[4][2];
#pragma unroll
    for (int nt = 0; nt < 2; ++nt) {
        const int qrow = qt * 128 + ws * 64 + nt * 32 + l32;
#pragma unroll
        for (int ks = 0; ks < 4; ++ks) {
            uint4 u = *(const uint4*)(Qp + (size_t)qrow * 64 + ks * 16 + hh * 8);
            union { uint4 u4; bf16x8 v; } w;
            w.u4.x = scale2bf(u.x, SC); w.u4.y = scale2bf(u.y, SC);
            w.u4.z = scale2bf(u.z, SC); w.u4.w = scale2bf(u.w, SC);
            qf[ks][nt] = w.v;
        }
    }

    floatx16 oacc[2][2];   // [dk-tile][q-tile], O^T
#pragma unroll
    for (int i = 0; i < 2; ++i)
#pragma unroll
        for (int j = 0; j < 2; ++j)
#pragma unroll
            for (int r = 0; r < 16; ++r) oacc[i][j][r] = 0.f;
    float lsA[2] = {0.f, 0.f}, lsB[2] = {0.f, 0.f};

    // stage one (K,V) pair for both groups into buffer d
    auto stage = [&](int d, int kt) {
#pragma unroll
        for (int t = 0; t < 8; ++t) {
            const int id = wid * 8 + t;
            const int gg = id >> 4;
            const int kv = (id >> 3) & 1;
            const int j  = id & 7;
            const int row = j * 8 + srow;
            const int sg  = (lane & 7) ^ srow ^ j;   // swizzle incl. row>>3 (=j)
            const int sk0 = (gg * 16 + kt) * 64;
            unsigned short* dstl = &smem[d * 16384 + gg * 8192 + kv * 4096 + j * 512];
            if (kv == 0)
                gload_lds16(Kp + (size_t)(sk0 + row) * 64 + sg * 8, dstl);
            else
                gload_lds16(Vp + (size_t)row * 2048 + sk0 + sg * 8, dstl);
        }
    };

    stage(0, 0);

    for (int kt = 0; kt < 16; ++kt) {
        __syncthreads();   // drains this buffer's loads (issued one compute-phase ago)
        if (kt < 15) stage((kt + 1) & 1, kt + 1);   // async prefetch into other buffer

        const int d = kt & 1;
        const unsigned short* Kb = &smem[d * 16384 + g * 8192];
        const unsigned short* Vb = &smem[d * 16384 + g * 8192 + 4096];

        // ---- S^T = K · Q^T ----
        floatx16 sc[2][2];
#pragma unroll
        for (int i = 0; i < 2; ++i)
#pragma unroll
            for (int j = 0; j < 2; ++j)
#pragma unroll
                for (int r = 0; r < 16; ++r) sc[i][j][r] = 0.f;
#pragma unroll
        for (int ks = 0; ks < 4; ++ks) {
            const int c = ks * 2 + hh;
            bf16x8 kf[2];
#pragma unroll
            for (int mt = 0; mt < 2; ++mt) {
                const int row = mt * 32 + l32;
                const int ch  = (c ^ (row & 7) ^ ((row >> 3) & 7)) * 8;
                kf[mt] = *(const bf16x8*)(&Kb[row * 64 + ch]);
            }
#pragma unroll
            for (int mt = 0; mt < 2; ++mt)
#pragma unroll
                for (int nt = 0; nt < 2; ++nt)
                    sc[mt][nt] = __builtin_amdgcn_mfma_f32_32x32x16_bf16(
                        kf[mt], qf[ks][nt], sc[mt][nt], 0, 0, 0);
        }

        // ---- p = 2^(s*SC), in-register lsum ----
#pragma unroll
        for (int st = 0; st < 2; ++st)
#pragma unroll
            for (int nt = 0; nt < 2; ++nt)
#pragma unroll
                for (int r = 0; r < 16; ++r) {
                    float p = __builtin_amdgcn_exp2f(sc[st][nt][r]);
                    sc[st][nt][r] = p;
                    if (r & 1) lsB[nt] += p; else lsA[nt] += p;
                }

        // ---- V^T fragments ----
        bf16x8 vf[2][4];
#pragma unroll
        for (int ksp = 0; ksp < 4; ++ksp) {
            const int c = ksp * 2 + hh;
#pragma unroll
            for (int vt = 0; vt < 2; ++vt) {
                const int row = vt * 32 + l32;
                const int ch  = (c ^ (row & 7) ^ ((row >> 3) & 7)) * 8;
                vf[vt][ksp] = *(const bf16x8*)(&Vb[row * 64 + ch]);
            }
        }

        // ---- O^T += V^T · P : B-frags via xor-32 exchanges ----
#pragma unroll
        for (int st = 0; st < 2; ++st)
#pragma unroll
            for (int nt = 0; nt < 2; ++nt) {
                int p[8];
#pragma unroll
                for (int i = 0; i < 8; ++i)
                    p[i] = (int)pack2bf(sc[st][nt][2 * i], sc[st][nt][2 * i + 1]);
                const int e0 = __shfl_xor(hh ? p[0] : p[2], 32, 64);
                const int e1 = __shfl_xor(hh ? p[1] : p[3], 32, 64);
                const int e2 = __shfl_xor(hh ? p[4] : p[6], 32, 64);
                const int e3 = __shfl_xor(hh ? p[5] : p[7], 32, 64);
                union { int i4[4]; bf16x8 v; } b0, b1;
                b0.i4[0] = hh ? e0 : p[0];
                b0.i4[1] = hh ? e1 : p[1];
                b0.i4[2] = hh ? p[2] : e0;
                b0.i4[3] = hh ? p[3] : e1;
                b1.i4[0] = hh ? e2 : p[4];
                b1.i4[1] = hh ? e3 : p[5];
                b1.i4[2] = hh ? p[6] : e2;
                b1.i4[3] = hh ? p[7] : e3;
                const int k0 = st * 2;
#pragma unroll
                for (int vt = 0; vt < 2; ++vt) {
                    oacc[vt][nt] = __builtin_amdgcn_mfma_f32_32x32x16_bf16(
                        vf[vt][k0], b0.v, oacc[vt][nt], 0, 0, 0);
                    oacc[vt][nt] = __builtin_amdgcn_mfma_f32_32x32x16_bf16(
                        vf[vt][k0 + 1], b1.v, oacc[vt][nt], 0, 0, 0);
                }
            }
    }

    // ---- merge group partials, normalize, store ----
    __syncthreads();
    float* pf = (float*)smem;                    // 2 x 64 x 68 floats = 34,816 B
    float* lf = (float*)(&smem[17408]);          // 256 floats @ byte 34,816
    if (g == 1) {
#pragma unroll
        for (int vt = 0; vt < 2; ++vt)
#pragma unroll
            for (int nt = 0; nt < 2; ++nt) {
                const int base = ws * 4352 + lane * 68 + (vt * 2 + nt) * 16;
#pragma unroll
                for (int r4 = 0; r4 < 4; ++r4) {
                    floatx4 t = {oacc[vt][nt][r4 * 4 + 0], oacc[vt][nt][r4 * 4 + 1],
                                 oacc[vt][nt][r4 * 4 + 2], oacc[vt][nt][r4 * 4 + 3]};
                    *(floatx4*)(&pf[base + r4 * 4]) = t;
                }
            }
        lf[ws * 128 + 0 * 64 + lane] = lsA[0] + lsB[0];
        lf[ws * 128 + 1 * 64 + lane] = lsA[1] + lsB[1];
    }
    __syncthreads();
    if (g == 0) {
        float linv[2];
#pragma unroll
        for (int nt = 0; nt < 2; ++nt) {
            float lm = lsA[nt] + lsB[nt] + lf[ws * 128 + nt * 64 + lane];
            lm += __shfl_xor(lm, 32, 64);
            linv[nt] = 1.0f / lm;
        }
#pragma unroll
        for (int vt = 0; vt < 2; ++vt)
#pragma unroll
            for (int nt = 0; nt < 2; ++nt) {
                const int base = ws * 4352 + lane * 68 + (vt * 2 + nt) * 16;
#pragma unroll
                for (int r4 = 0; r4 < 4; ++r4) {
                    floatx4 t = *(const floatx4*)(&pf[base + r4 * 4]);
#pragma unroll
                    for (int e = 0; e < 4; ++e)
                        oacc[vt][nt][r4 * 4 + e] =
                            (oacc[vt][nt][r4 * 4 + e] + t[e]) * linv[nt];
                }
            }
    }
    __syncthreads();
    // O^T -> LDS [q 128][dk 64] (stride 72), bf16
    if (g == 0) {
#pragma unroll
        for (int vt = 0; vt < 2; ++vt)
#pragma unroll
            for (int nt = 0; nt < 2; ++nt) {
                const int qrow = ws * 64 + nt * 32 + l32;
#pragma unroll
                for (int i = 0; i < 8; ++i) {
                    const int dko = vt * 32 + 8 * (i >> 1) + 2 * (i & 1) + 4 * hh;
                    *(unsigned int*)(&smem[qrow * 72 + dko]) =
                        pack2bf(oacc[vt][nt][2 * i], oacc[vt][nt][2 * i + 1]);
                }
            }
    }
    __syncthreads();
    // coalesced store: 128 rows x 128 B
#pragma unroll
    for (int i = 0; i < 4; ++i) {
        const int idx = i * 256 + tid;
        const int row = idx >> 3;
        const int c   = idx & 7;
        *(uint4*)(AO + ((size_t)b * SEQ + qt * 128 + row) * 512 + h * 64 + c * 8) =
            *(const uint4*)(&smem[row * 72 + c * 8]);
    }
}

// ---------------------------------------------------------------------------
// Kernel 3: output projection. out = AO(bf16) @ wo^T + bo, fp32 out.
// A via glds (swizzled); B (wo, fp32) via register staging -> stride-72 LDS.
// Tile 64x128, grid (4, 128), BK=64.
// ---------------------------------------------------------------------------
__global__ __launch_bounds__(256) void outproj_kernel(
    const unsigned short* __restrict__ AO, const float* __restrict__ wo,
    const float* __restrict__ bo, float* __restrict__ out)
{
    const int n0 = blockIdx.x * 128;
    const int m0 = blockIdx.y * 64;

    // A 64x64 swizzled @0 (4096 shorts), B 128x[64+pad8] @4096 (9216 shorts)
    __shared__ unsigned short lds[13312];

    const int tid  = threadIdx.x;
    const int lane = tid & 63;
    const int wid  = tid >> 6;
    const int quad = lane >> 4;
    const int l16  = lane & 15;
    const int wr   = (wid >> 1) * 32;
    const int wc   = (wid & 1) * 64;

    const int srow8 = lane >> 3;
    const int scg   = (lane & 7) ^ srow8;

    floatx4 acc[2][4];
#pragma unroll
    for (int i = 0; i < 2; ++i)
#pragma unroll
        for (int j = 0; j < 4; ++j) acc[i][j] = {0.f, 0.f, 0.f, 0.f};

    for (int kt = 0; kt < 8; ++kt) {
        const int kk0 = kt * 64;
        __syncthreads();
        // A: 8 glds insts (2/wave)
#pragma unroll
        for (int t = 0; t < 2; ++t) {
            const int i = wid * 2 + t;
            const int row = i * 8 + srow8;
            gload_lds16(AO + (size_t)(m0 + row) * 512 + kk0 + scg * 8, &lds[i * 512]);
        }
        // B: 128x64 fp32 -> bf16, 8 float4/thread
#pragma unroll
        for (int i = 0; i < 8; ++i) {
            int f   = tid + i * 256;         // 0..2047
            int row = f >> 4;                // 0..127
            int col = (f & 15) * 4;          // 0..60
            float4 b4 = *(const float4*)(wo + (size_t)(n0 + row) * 512 + kk0 + col);
            uint2 bp2; bp2.x = pack2bf(b4.x, b4.y); bp2.y = pack2bf(b4.z, b4.w);
            *(uint2*)(&lds[4096 + row * 72 + col]) = bp2;
        }
        __syncthreads();

        bf16x8 af[2][2], bfr[4][2];
#pragma unroll
        for (int kk = 0; kk < 2; ++kk) {
            const int c = kk * 4 + quad;
#pragma unroll
            for (int mi = 0; mi < 2; ++mi) {
                const int rA = wr + mi * 16 + l16;
                af[mi][kk] = *(const bf16x8*)(&lds[rA * 64 + ((c ^ (rA & 7)) * 8)]);
            }
#pragma unroll
            for (int ni = 0; ni < 4; ++ni) {
                const int rB = wc + ni * 16 + l16;
                bfr[ni][kk] = *(const bf16x8*)(&lds[4096 + rB * 72 + c * 8]);
            }
        }
#pragma unroll
        for (int kk = 0; kk < 2; ++kk)
#pragma unroll
            for (int mi = 0; mi < 2; ++mi)
#pragma unroll
                for (int ni = 0; ni < 4; ++ni)
                    acc[mi][ni] = __builtin_amdgcn_mfma_f32_16x16x32_bf16(
                        af[mi][kk], bfr[ni][kk], acc[mi][ni], 0, 0, 0);
    }

#pragma unroll
    for (int mi = 0; mi < 2; ++mi)
#pragma unroll
        for (int ni = 0; ni < 4; ++ni) {
            const int n = n0 + wc + ni * 16 + l16;
            const float bsv = bo[n];
#pragma unroll
            for (int r = 0; r < 4; ++r) {
                const int m = m0 + wr + mi * 16 + quad * 4 + r;
                out[(size_t)m * 512 + n] = acc[mi][ni][r] + bsv;
            }
        }
}

// ---------------------------------------------------------------------------
extern "C" void kernel_launch(void* const* d_in, const int* in_sizes, int n_in,
                              void* d_out, int out_size, void* d_ws, size_t ws_size,
                              hipStream_t stream) {
    const float* q  = (const float*)d_in[0];
    const float* k  = (const float*)d_in[1];
    const float* v  = (const float*)d_in[2];
    const float* wq = (const float*)d_in[3];
    const float* wk = (const float*)d_in[4];
    const float* wv = (const float*)d_in[5];
    const float* wo = (const float*)d_in[6];
    const float* bq = (const float*)d_in[7];
    const float* bk = (const float*)d_in[8];
    const float* bv = (const float*)d_in[9];
    const float* bo = (const float*)d_in[10];

    const size_t headElems = (size_t)NB * NH * SEQ * DK;   // 4,194,304
    unsigned short* Qh  = (unsigned short*)d_ws;
    unsigned short* Kh  = Qh + headElems;
    unsigned short* VhT = Kh + headElems;
    unsigned short* AO  = VhT + headElems;
    float* out = (float*)d_out;

    proj_qkv_kernel<<<dim3(4, 64, 3), 256, 0, stream>>>(
        q, k, v, wq, wk, wv, bq, bk, bv, Qh, Kh, VhT);
    flash_kernel<<<dim3(SEQ / 128, NH, NB), 256, 0, stream>>>(Qh, Kh, VhT, AO);
    outproj_kernel<<<dim3(4, 128), 256, 0, stream>>>(AO, wo, bo, out);
}

// Round 7
// 195.682 us; speedup vs baseline: 1.1053x; 1.1053x over previous
//
#include <hip/hip_runtime.h>

#define D_MODEL 512
#define NH 8
#define DK 64
#define SEQ 2048
#define NB 4

typedef __bf16 bf16x8 __attribute__((ext_vector_type(8)));
typedef float floatx4 __attribute__((ext_vector_type(4)));
typedef float floatx16 __attribute__((ext_vector_type(16)));

typedef __attribute__((address_space(1))) const unsigned int glb_u32;
typedef __attribute__((address_space(3))) unsigned int lds_u32;

__device__ __forceinline__ void gload_lds16(const unsigned short* g, unsigned short* l) {
    __builtin_amdgcn_global_load_lds((glb_u32*)g, (lds_u32*)l, 16, 0, 0);
}

// round-half-up bf16, packed pair via v_perm
__device__ inline unsigned int pack2bf(float lo, float hi) {
    unsigned int a = __float_as_uint(lo) + 0x8000u;
    unsigned int b = __float_as_uint(hi) + 0x8000u;
    return __builtin_amdgcn_perm(b, a, 0x07060302u);
}
__device__ inline unsigned short f2bf(float f) {
    return (unsigned short)((__float_as_uint(f) + 0x8000u) >> 16);
}
// scale a packed bf16 pair by s, repack
__device__ inline unsigned int scale2bf(unsigned int u, float s) {
    float lo = __uint_as_float(u << 16) * s;
    float hi = __uint_as_float(u & 0xFFFF0000u) * s;
    return pack2bf(lo, hi);
}

// ---------------------------------------------------------------------------
// Kernel 0: fp32 -> bf16 convert. X = q|k|v (3 x 8192x512), W = wq|wk|wv|wo.
// ---------------------------------------------------------------------------
__global__ __launch_bounds__(256) void convert_kernel(
    const float* __restrict__ q, const float* __restrict__ k, const float* __restrict__ v,
    const float* __restrict__ wq, const float* __restrict__ wk, const float* __restrict__ wv,
    const float* __restrict__ wo, unsigned short* __restrict__ Xbf,
    unsigned short* __restrict__ Wbf)
{
    const int bid = blockIdx.x;
    const float* src;
    unsigned short* dst;
    size_t off;
    if (bid < 6144) {
        const int which = bid >> 11;
        src = (which == 0) ? q : (which == 1) ? k : v;
        dst = Xbf + (size_t)which * 4194304;
        off = ((size_t)(bid & 2047) * 256 + threadIdx.x) * 8;
    } else {
        const int wb = bid - 6144;
        const int which = wb >> 7;
        src = (which == 0) ? wq : (which == 1) ? wk : (which == 2) ? wv : wo;
        dst = Wbf + (size_t)which * 262144;
        off = ((size_t)(wb & 127) * 256 + threadIdx.x) * 8;
    }
    float4 a = *(const float4*)(src + off);
    float4 b = *(const float4*)(src + off + 4);
    uint4 r;
    r.x = pack2bf(a.x, a.y); r.y = pack2bf(a.z, a.w);
    r.z = pack2bf(b.x, b.y); r.w = pack2bf(b.z, b.w);
    *(uint4*)(dst + off) = r;
}

// ---------------------------------------------------------------------------
// Kernel 1: QKV projection GEMM, bf16 in, global_load_lds staging, swizzled LDS.
// C[8192][512] = Xbf @ Wbf^T + b.  Q,K -> [b,h,s,dk]; V -> [b,h,dk,s].
// grid (4, 64, 3), block 256, tile 128x128, BK=64.
// ---------------------------------------------------------------------------
__global__ __launch_bounds__(256) void proj_qkv_kernel(
    const unsigned short* __restrict__ Xbf, const unsigned short* __restrict__ Wbf,
    const float* __restrict__ bq, const float* __restrict__ bk, const float* __restrict__ bv,
    unsigned short* __restrict__ Qh, unsigned short* __restrict__ Kh,
    unsigned short* __restrict__ VhT)
{
    const int which = blockIdx.z;
    const unsigned short* A = Xbf + (size_t)which * 4194304;
    const unsigned short* B = Wbf + (size_t)which * 262144;
    const float* bias = (which == 0) ? bq : (which == 1) ? bk : bv;

    const int n0 = blockIdx.x * 128;
    const int m0 = blockIdx.y * 128;

    __shared__ unsigned short lds[17408];

    const int tid  = threadIdx.x;
    const int lane = tid & 63;
    const int wid  = tid >> 6;
    const int quad = lane >> 4;
    const int l16  = lane & 15;
    const int wr   = (wid >> 1) * 64;
    const int wc   = (wid & 1) * 64;

    const int srow8 = lane >> 3;
    const int scg   = (lane & 7) ^ (srow8 & 7);

    floatx4 acc[4][4];
#pragma unroll
    for (int i = 0; i < 4; ++i)
#pragma unroll
        for (int j = 0; j < 4; ++j) acc[i][j] = {0.f, 0.f, 0.f, 0.f};

    for (int kt = 0; kt < 8; ++kt) {
        const int kk0 = kt * 64;
        __syncthreads();
#pragma unroll
        for (int t = 0; t < 4; ++t) {
            const int i = wid * 4 + t;
            const int row = i * 8 + srow8;
            gload_lds16(A + (size_t)(m0 + row) * 512 + kk0 + scg * 8, &lds[i * 512]);
            gload_lds16(B + (size_t)(n0 + row) * 512 + kk0 + scg * 8, &lds[8192 + i * 512]);
        }
        __syncthreads();

        bf16x8 af[4][2], bf[4][2];
#pragma unroll
        for (int kk = 0; kk < 2; ++kk) {
            const int c = kk * 4 + quad;
#pragma unroll
            for (int mi = 0; mi < 4; ++mi) {
                const int rA = wr + mi * 16 + l16;
                af[mi][kk] = *(const bf16x8*)(&lds[rA * 64 + ((c ^ (rA & 7)) * 8)]);
            }
#pragma unroll
            for (int ni = 0; ni < 4; ++ni) {
                const int rB = wc + ni * 16 + l16;
                bf[ni][kk] = *(const bf16x8*)(&lds[8192 + rB * 64 + ((c ^ (rB & 7)) * 8)]);
            }
        }
#pragma unroll
        for (int kk = 0; kk < 2; ++kk)
#pragma unroll
            for (int mi = 0; mi < 4; ++mi)
#pragma unroll
                for (int ni = 0; ni < 4; ++ni)
                    acc[mi][ni] = __builtin_amdgcn_mfma_f32_16x16x32_bf16(
                        af[mi][kk], bf[ni][kk], acc[mi][ni], 0, 0, 0);
    }

    float bs[4];
#pragma unroll
    for (int ni = 0; ni < 4; ++ni) bs[ni] = bias[n0 + wc + ni * 16 + l16];

    __syncthreads();
#pragma unroll
    for (int mi = 0; mi < 4; ++mi)
#pragma unroll
        for (int ni = 0; ni < 4; ++ni)
#pragma unroll
            for (int r = 0; r < 4; ++r)
                lds[(wr + mi * 16 + quad * 4 + r) * 136 + wc + ni * 16 + l16] =
                    f2bf(acc[mi][ni][r] + bs[ni]);
    __syncthreads();

    const int b = m0 >> 11;
    if (which != 2) {
        unsigned short* dst = (which == 0) ? Qh : Kh;
#pragma unroll
        for (int j = 0; j < 8; ++j) {
            const int chunk = j * 256 + tid;
            const int srow  = chunk >> 4;
            const int col   = (chunk & 15) * 8;
            const int h  = (n0 + col) >> 6;
            const int dk = col & 63;
            const int s  = (m0 & 2047) + srow;
            uint4 vv = *(const uint4*)(&lds[srow * 136 + col]);
            *(uint4*)(dst + ((size_t)(b * NH + h) * SEQ + s) * DK + dk) = vv;
        }
    } else {
#pragma unroll
        for (int j = 0; j < 8; ++j) {
            const int chunk = j * 256 + tid;
            const int d    = chunk >> 4;
            const int sc8  = (chunk & 15) * 8;
            const int h  = (n0 + d) >> 6;
            const int dk = (n0 + d) & 63;
            unsigned short tmp[8];
#pragma unroll
            for (int i = 0; i < 8; ++i) tmp[i] = lds[(sc8 + i) * 136 + d];
            const size_t s0 = (size_t)(m0 & 2047) + sc8;
            *(uint4*)(VhT + ((size_t)(b * NH + h) * DK + dk) * SEQ + s0) = *(const uint4*)tmp;
        }
    }
}

// ---------------------------------------------------------------------------
// Kernel 2: flash attention — R4 structure (single-buffered staging, q-tile
// 128, 2 kg x 2 qw(64 rows), grid (16,8,4)) + full XOR swizzle (^row ^row>>3)
// from R6 (proven: conflicts 2.2M -> 98K).
// ---------------------------------------------------------------------------
__global__ __launch_bounds__(256, 2) void flash_kernel(
    const unsigned short* __restrict__ Qh, const unsigned short* __restrict__ Kh,
    const unsigned short* __restrict__ VhT, unsigned short* __restrict__ AO)
{
    const int qt = blockIdx.x, h = blockIdx.y, b = blockIdx.z;
    const size_t bh = (size_t)b * NH + h;
    const unsigned short* Qp = Qh + bh * SEQ * DK;
    const unsigned short* Kp = Kh + bh * SEQ * DK;
    const unsigned short* Vp = VhT + bh * DK * SEQ;

    // staging (shorts): [g][ K 64x64 | V 64x64 ] @ g*8192; epilogue reuses all
    __shared__ unsigned short smem[17920];   // 35,840 B

    const int tid  = threadIdx.x;
    const int lane = tid & 63;
    const int wid  = tid >> 6;
    const int g    = wid >> 1;    // k-group
    const int ws   = wid & 1;     // q-half (64 rows)
    const int hh   = lane >> 5;
    const int l32  = lane & 31;
    const int srow = lane >> 3;

    // ---- persistent Q fragments, pre-scaled by 0.125*log2(e) ----
    const float SC = 0.18033688f;
    bf16x8 qf[4][2];
#pragma unroll
    for (int nt = 0; nt < 2; ++nt) {
        const int qrow = qt * 128 + ws * 64 + nt * 32 + l32;
#pragma unroll
        for (int ks = 0; ks < 4; ++ks) {
            uint4 u = *(const uint4*)(Qp + (size_t)qrow * 64 + ks * 16 + hh * 8);
            union { uint4 u4; bf16x8 v; } w;
            w.u4.x = scale2bf(u.x, SC); w.u4.y = scale2bf(u.y, SC);
            w.u4.z = scale2bf(u.z, SC); w.u4.w = scale2bf(u.w, SC);
            qf[ks][nt] = w.v;
        }
    }

    floatx16 oacc[2][2];   // [dk-tile][q-tile], O^T
#pragma unroll
    for (int i = 0; i < 2; ++i)
#pragma unroll
        for (int j = 0; j < 2; ++j)
#pragma unroll
            for (int r = 0; r < 16; ++r) oacc[i][j][r] = 0.f;
    float lsA[2] = {0.f, 0.f}, lsB[2] = {0.f, 0.f};

    for (int kt = 0; kt < 16; ++kt) {
        __syncthreads();
        // stage both groups' K and V tiles: 32 wave-insts, 8 per wave
#pragma unroll
        for (int t = 0; t < 8; ++t) {
            const int id = wid * 8 + t;
            const int gg = id >> 4;
            const int kv = (id >> 3) & 1;
            const int j  = id & 7;
            const int row = j * 8 + srow;
            const int sg  = (lane & 7) ^ srow ^ j;   // XOR swizzle incl. row>>3 (=j)
            const int sk0 = (gg * 16 + kt) * 64;
            unsigned short* dstl = &smem[gg * 8192 + kv * 4096 + j * 512];
            if (kv == 0)
                gload_lds16(Kp + (size_t)(sk0 + row) * 64 + sg * 8, dstl);
            else
                gload_lds16(Vp + (size_t)row * 2048 + sk0 + sg * 8, dstl);
        }
        __syncthreads();

        const unsigned short* Kb = &smem[g * 8192];
        const unsigned short* Vb = &smem[g * 8192 + 4096];

        // ---- S^T = K · Q^T ----
        floatx16 sc[2][2];
#pragma unroll
        for (int i = 0; i < 2; ++i)
#pragma unroll
            for (int j = 0; j < 2; ++j)
#pragma unroll
                for (int r = 0; r < 16; ++r) sc[i][j][r] = 0.f;
#pragma unroll
        for (int ks = 0; ks < 4; ++ks) {
            const int c = ks * 2 + hh;
            bf16x8 kf[2];
#pragma unroll
            for (int mt = 0; mt < 2; ++mt) {
                const int row = mt * 32 + l32;
                const int ch  = (c ^ (row & 7) ^ ((row >> 3) & 7)) * 8;
                kf[mt] = *(const bf16x8*)(&Kb[row * 64 + ch]);
            }
#pragma unroll
            for (int mt = 0; mt < 2; ++mt)
#pragma unroll
                for (int nt = 0; nt < 2; ++nt)
                    sc[mt][nt] = __builtin_amdgcn_mfma_f32_32x32x16_bf16(
                        kf[mt], qf[ks][nt], sc[mt][nt], 0, 0, 0);
        }

        // ---- p = 2^(s*SC), in-register lsum ----
#pragma unroll
        for (int st = 0; st < 2; ++st)
#pragma unroll
            for (int nt = 0; nt < 2; ++nt)
#pragma unroll
                for (int r = 0; r < 16; ++r) {
                    float p = __builtin_amdgcn_exp2f(sc[st][nt][r]);
                    sc[st][nt][r] = p;
                    if (r & 1) lsB[nt] += p; else lsA[nt] += p;
                }

        // ---- V^T fragments ----
        bf16x8 vf[2][4];
#pragma unroll
        for (int ksp = 0; ksp < 4; ++ksp) {
            const int c = ksp * 2 + hh;
#pragma unroll
            for (int vt = 0; vt < 2; ++vt) {
                const int row = vt * 32 + l32;
                const int ch  = (c ^ (row & 7) ^ ((row >> 3) & 7)) * 8;
                vf[vt][ksp] = *(const bf16x8*)(&Vb[row * 64 + ch]);
            }
        }

        // ---- O^T += V^T · P : B-frags via xor-32 exchanges ----
#pragma unroll
        for (int st = 0; st < 2; ++st)
#pragma unroll
            for (int nt = 0; nt < 2; ++nt) {
                int p[8];
#pragma unroll
                for (int i = 0; i < 8; ++i)
                    p[i] = (int)pack2bf(sc[st][nt][2 * i], sc[st][nt][2 * i + 1]);
                const int e0 = __shfl_xor(hh ? p[0] : p[2], 32, 64);
                const int e1 = __shfl_xor(hh ? p[1] : p[3], 32, 64);
                const int e2 = __shfl_xor(hh ? p[4] : p[6], 32, 64);
                const int e3 = __shfl_xor(hh ? p[5] : p[7], 32, 64);
                union { int i4[4]; bf16x8 v; } b0, b1;
                b0.i4[0] = hh ? e0 : p[0];
                b0.i4[1] = hh ? e1 : p[1];
                b0.i4[2] = hh ? p[2] : e0;
                b0.i4[3] = hh ? p[3] : e1;
                b1.i4[0] = hh ? e2 : p[4];
                b1.i4[1] = hh ? e3 : p[5];
                b1.i4[2] = hh ? p[6] : e2;
                b1.i4[3] = hh ? p[7] : e3;
                const int k0 = st * 2;
#pragma unroll
                for (int vt = 0; vt < 2; ++vt) {
                    oacc[vt][nt] = __builtin_amdgcn_mfma_f32_32x32x16_bf16(
                        vf[vt][k0], b0.v, oacc[vt][nt], 0, 0, 0);
                    oacc[vt][nt] = __builtin_amdgcn_mfma_f32_32x32x16_bf16(
                        vf[vt][k0 + 1], b1.v, oacc[vt][nt], 0, 0, 0);
                }
            }
    }

    // ---- merge group partials, normalize, store ----
    __syncthreads();
    float* pf = (float*)smem;                    // 2 x 64 x 68 floats = 34,816 B
    float* lf = (float*)(&smem[17408]);          // 256 floats @ byte 34,816
    if (g == 1) {
#pragma unroll
        for (int vt = 0; vt < 2; ++vt)
#pragma unroll
            for (int nt = 0; nt < 2; ++nt) {
                const int base = ws * 4352 + lane * 68 + (vt * 2 + nt) * 16;
#pragma unroll
                for (int r4 = 0; r4 < 4; ++r4) {
                    floatx4 t = {oacc[vt][nt][r4 * 4 + 0], oacc[vt][nt][r4 * 4 + 1],
                                 oacc[vt][nt][r4 * 4 + 2], oacc[vt][nt][r4 * 4 + 3]};
                    *(floatx4*)(&pf[base + r4 * 4]) = t;
                }
            }
        lf[ws * 128 + 0 * 64 + lane] = lsA[0] + lsB[0];
        lf[ws * 128 + 1 * 64 + lane] = lsA[1] + lsB[1];
    }
    __syncthreads();
    if (g == 0) {
        float linv[2];
#pragma unroll
        for (int nt = 0; nt < 2; ++nt) {
            float lm = lsA[nt] + lsB[nt] + lf[ws * 128 + nt * 64 + lane];
            lm += __shfl_xor(lm, 32, 64);
            linv[nt] = 1.0f / lm;
        }
#pragma unroll
        for (int vt = 0; vt < 2; ++vt)
#pragma unroll
            for (int nt = 0; nt < 2; ++nt) {
                const int base = ws * 4352 + lane * 68 + (vt * 2 + nt) * 16;
#pragma unroll
                for (int r4 = 0; r4 < 4; ++r4) {
                    floatx4 t = *(const floatx4*)(&pf[base + r4 * 4]);
#pragma unroll
                    for (int e = 0; e < 4; ++e)
                        oacc[vt][nt][r4 * 4 + e] =
                            (oacc[vt][nt][r4 * 4 + e] + t[e]) * linv[nt];
                }
            }
    }
    __syncthreads();
    // O^T -> LDS [q 128][dk 64] (stride 72), bf16
    if (g == 0) {
#pragma unroll
        for (int vt = 0; vt < 2; ++vt)
#pragma unroll
            for (int nt = 0; nt < 2; ++nt) {
                const int qrow = ws * 64 + nt * 32 + l32;
#pragma unroll
                for (int i = 0; i < 8; ++i) {
                    const int dko = vt * 32 + 8 * (i >> 1) + 2 * (i & 1) + 4 * hh;
                    *(unsigned int*)(&smem[qrow * 72 + dko]) =
                        pack2bf(oacc[vt][nt][2 * i], oacc[vt][nt][2 * i + 1]);
                }
            }
    }
    __syncthreads();
    // coalesced store: 128 rows x 128 B
#pragma unroll
    for (int i = 0; i < 4; ++i) {
        const int idx = i * 256 + tid;
        const int row = idx >> 3;
        const int c   = idx & 7;
        *(uint4*)(AO + ((size_t)b * SEQ + qt * 128 + row) * 512 + h * 64 + c * 8) =
            *(const uint4*)(&smem[row * 72 + c * 8]);
    }
}

// ---------------------------------------------------------------------------
// Kernel 3: output projection. out = AO(bf16) @ wo_bf^T + bo, fp32 out.
// Tile 64x128, grid (4, 128), BK=64, global_load_lds staging.
// ---------------------------------------------------------------------------
__global__ __launch_bounds__(256) void outproj_kernel(
    const unsigned short* __restrict__ AO, const unsigned short* __restrict__ Wbf,
    const float* __restrict__ bo, float* __restrict__ out)
{
    const unsigned short* B = Wbf + (size_t)3 * 262144;
    const int n0 = blockIdx.x * 128;
    const int m0 = blockIdx.y * 64;

    __shared__ unsigned short lds[12288];

    const int tid  = threadIdx.x;
    const int lane = tid & 63;
    const int wid  = tid >> 6;
    const int quad = lane >> 4;
    const int l16  = lane & 15;
    const int wr   = (wid >> 1) * 32;
    const int wc   = (wid & 1) * 64;

    const int srow8 = lane >> 3;
    const int scg   = (lane & 7) ^ (srow8 & 7);

    floatx4 acc[2][4];
#pragma unroll
    for (int i = 0; i < 2; ++i)
#pragma unroll
        for (int j = 0; j < 4; ++j) acc[i][j] = {0.f, 0.f, 0.f, 0.f};

    for (int kt = 0; kt < 8; ++kt) {
        const int kk0 = kt * 64;
        __syncthreads();
#pragma unroll
        for (int t = 0; t < 2; ++t) {
            const int i = wid * 2 + t;
            const int row = i * 8 + srow8;
            gload_lds16(AO + (size_t)(m0 + row) * 512 + kk0 + scg * 8, &lds[i * 512]);
        }
#pragma unroll
        for (int t = 0; t < 4; ++t) {
            const int i = wid * 4 + t;
            const int row = i * 8 + srow8;
            gload_lds16(B + (size_t)(n0 + row) * 512 + kk0 + scg * 8, &lds[4096 + i * 512]);
        }
        __syncthreads();

        bf16x8 af[2][2], bf[4][2];
#pragma unroll
        for (int kk = 0; kk < 2; ++kk) {
            const int c = kk * 4 + quad;
#pragma unroll
            for (int mi = 0; mi < 2; ++mi) {
                const int rA = wr + mi * 16 + l16;
                af[mi][kk] = *(const bf16x8*)(&lds[rA * 64 + ((c ^ (rA & 7)) * 8)]);
            }
#pragma unroll
            for (int ni = 0; ni < 4; ++ni) {
                const int rB = wc + ni * 16 + l16;
                bf[ni][kk] = *(const bf16x8*)(&lds[4096 + rB * 64 + ((c ^ (rB & 7)) * 8)]);
            }
        }
#pragma unroll
        for (int kk = 0; kk < 2; ++kk)
#pragma unroll
            for (int mi = 0; mi < 2; ++mi)
#pragma unroll
                for (int ni = 0; ni < 4; ++ni)
                    acc[mi][ni] = __builtin_amdgcn_mfma_f32_16x16x32_bf16(
                        af[mi][kk], bf[ni][kk], acc[mi][ni], 0, 0, 0);
    }

#pragma unroll
    for (int mi = 0; mi < 2; ++mi)
#pragma unroll
        for (int ni = 0; ni < 4; ++ni) {
            const int n = n0 + wc + ni * 16 + l16;
            const float bsv = bo[n];
#pragma unroll
            for (int r = 0; r < 4; ++r) {
                const int m = m0 + wr + mi * 16 + quad * 4 + r;
                out[(size_t)m * 512 + n] = acc[mi][ni][r] + bsv;
            }
        }
}

// ---------------------------------------------------------------------------
extern "C" void kernel_launch(void* const* d_in, const int* in_sizes, int n_in,
                              void* d_out, int out_size, void* d_ws, size_t ws_size,
                              hipStream_t stream) {
    const float* q  = (const float*)d_in[0];
    const float* k  = (const float*)d_in[1];
    const float* v  = (const float*)d_in[2];
    const float* wq = (const float*)d_in[3];
    const float* wk = (const float*)d_in[4];
    const float* wv = (const float*)d_in[5];
    const float* wo = (const float*)d_in[6];
    const float* bq = (const float*)d_in[7];
    const float* bk = (const float*)d_in[8];
    const float* bv = (const float*)d_in[9];
    const float* bo = (const float*)d_in[10];

    const size_t headElems = (size_t)NB * NH * SEQ * DK;   // 4,194,304
    unsigned short* Qh  = (unsigned short*)d_ws;
    unsigned short* Kh  = Qh + headElems;
    unsigned short* VhT = Kh + headElems;
    unsigned short* AO  = VhT + headElems;
    unsigned short* Xbf = AO + headElems;
    unsigned short* Wbf = Xbf + 3 * headElems;
    float* out = (float*)d_out;

    convert_kernel<<<dim3(6656), 256, 0, stream>>>(q, k, v, wq, wk, wv, wo, Xbf, Wbf);
    proj_qkv_kernel<<<dim3(4, 64, 3), 256, 0, stream>>>(
        Xbf, Wbf, bq, bk, bv, Qh, Kh, VhT);
    flash_kernel<<<dim3(SEQ / 128, NH, NB), 256, 0, stream>>>(Qh, Kh, VhT, AO);
    outproj_kernel<<<dim3(4, 128), 256, 0, stream>>>(AO, Wbf, bo, out);
}